// Round 5
// baseline (363.501 us; speedup 1.0000x reference)
//
#include <hip/hip_runtime.h>
#include <stdint.h>

typedef unsigned short ushort_t;
typedef __attribute__((ext_vector_type(8))) short s8v;
typedef __attribute__((ext_vector_type(4))) float f4v;

#define NH 32
#define NKV 8
#define HD 64
#define S_LEN 2048
#define HID 2048
#define DQKV 3072

// 0.125 (HD^-0.5) * log2(e): softmax runs in exp2 domain
#define QSCALE 0.18033688011112042f

__device__ __forceinline__ ushort_t f2b(float f) {
  union { float f; unsigned u; } v; v.f = f;
  unsigned r = v.u + 0x7FFFu + ((v.u >> 16) & 1u);
  return (ushort_t)(r >> 16);
}
__device__ __forceinline__ unsigned cvtpk(float lo, float hi) {
  unsigned r;
  asm("v_cvt_pk_bf16_f32 %0, %1, %2" : "=v"(r) : "v"(lo), "v"(hi));
  return r;
}

// ---------------- fused f32 -> bf16 convert for x, Wqkv, Wo ----------------
__global__ void cvt3(const float* __restrict__ a, const float* __restrict__ b,
                     const float* __restrict__ c, ushort_t* __restrict__ oa,
                     ushort_t* __restrict__ ob, ushort_t* __restrict__ oc) {
  const int n1 = 1048576, n2 = 1572864;  // x/4, wqkv/4 (wo/4 = n1)
  int i = blockIdx.x * blockDim.x + threadIdx.x;
  const float* in; ushort_t* out; int j;
  if (i < n1) { in = a; out = oa; j = i; }
  else if (i < n1 + n2) { in = b; out = ob; j = i - n1; }
  else { in = c; out = oc; j = i - n1 - n2; }
  float4 v = ((const float4*)in)[j];
  uint2 p;
  p.x = cvtpk(v.x, v.y);
  p.y = cvtpk(v.z, v.w);
  ((uint2*)out)[j] = p;
}

// ---------------- split-K GEMM: C[M,N] += A[M,K_half] * B[N,K_half]^T ----------------
// 128x128 tile, BK=32, 4 waves; blockIdx.z selects K half; f32 atomic epilogue
// (C pre-zeroed; each element receives exactly 2 adds -> deterministic).
__global__ __launch_bounds__(256) void gemm_bt_sk(
    const ushort_t* __restrict__ A, const ushort_t* __restrict__ B,
    float* __restrict__ C, int M, int N, int K) {
  __shared__ ushort_t sA[128 * 32];
  __shared__ ushort_t sB[128 * 32];
  const int tid = threadIdx.x;
  const int wave = tid >> 6, lane = tid & 63;
  const int bm = blockIdx.y * 128, bn = blockIdx.x * 128;
  const int wm = (wave >> 1) * 64, wn = (wave & 1) * 64;
  const int srow = wave * 16 + (lane >> 2);
  const int scol = (lane & 3) * 8;
  const int fr = lane & 15, fg = lane >> 4;
  const int khalf = K >> 1;
  const int kbeg = blockIdx.z * khalf;

  f4v acc[4][4];
#pragma unroll
  for (int m = 0; m < 4; ++m)
#pragma unroll
    for (int n = 0; n < 4; ++n) acc[m][n] = (f4v){0.f, 0.f, 0.f, 0.f};

  for (int k0 = kbeg; k0 < kbeg + khalf; k0 += 32) {
    __syncthreads();
#pragma unroll
    for (int it = 0; it < 2; ++it) {
      int r = it * 64 + srow;
      __builtin_amdgcn_global_load_lds(
          (const __attribute__((address_space(1))) void*)(A + (size_t)(bm + r) * K + k0 + scol),
          (__attribute__((address_space(3))) void*)(&sA[(it * 64 + wave * 16) * 32]),
          16, 0, 0);
      __builtin_amdgcn_global_load_lds(
          (const __attribute__((address_space(1))) void*)(B + (size_t)(bn + r) * K + k0 + scol),
          (__attribute__((address_space(3))) void*)(&sB[(it * 64 + wave * 16) * 32]),
          16, 0, 0);
    }
    __syncthreads();

    s8v af[4], bf[4];
#pragma unroll
    for (int m = 0; m < 4; ++m)
      af[m] = *(const s8v*)&sA[(wm + m * 16 + fr) * 32 + fg * 8];
#pragma unroll
    for (int n = 0; n < 4; ++n)
      bf[n] = *(const s8v*)&sB[(wn + n * 16 + fr) * 32 + fg * 8];
#pragma unroll
    for (int m = 0; m < 4; ++m)
#pragma unroll
      for (int n = 0; n < 4; ++n)
        acc[m][n] = __builtin_amdgcn_mfma_f32_16x16x32_bf16(af[m], bf[n], acc[m][n], 0, 0, 0);
  }

#pragma unroll
  for (int m = 0; m < 4; ++m)
#pragma unroll
    for (int n = 0; n < 4; ++n)
#pragma unroll
      for (int rr = 0; rr < 4; ++rr) {
        int row = bm + wm + m * 16 + fg * 4 + rr;
        int col = bn + wn + n * 16 + fr;
        unsafeAtomicAdd(&C[(size_t)row * N + col], acc[m][n][rr]);
      }
}

// ---------------- RoPE on q,k (reads f32 qkv, writes bf16 Q,K) ----------------
__global__ void rope_qk(const float* __restrict__ qkvF, const float* __restrict__ fc,
                        ushort_t* __restrict__ Qb, ushort_t* __restrict__ Kb) {
  int tid = blockIdx.x * blockDim.x + threadIdx.x;
  if (tid >= S_LEN * 160) return;           // (NH+NKV) heads * 4 parts of 16
  int s = tid / 160, c = tid - s * 160;
  int h = c >> 2, part = c & 3;
  const float* src = qkvF + (size_t)s * DQKV + h * 64 + part * 16;
  float xv[16];
  ((float4*)xv)[0] = ((const float4*)src)[0];
  ((float4*)xv)[1] = ((const float4*)src)[1];
  ((float4*)xv)[2] = ((const float4*)src)[2];
  ((float4*)xv)[3] = ((const float4*)src)[3];
  const float* fp = fc + s * 64 + part * 16;
  float fv[16];
  ((float4*)fv)[0] = ((const float4*)fp)[0];
  ((float4*)fv)[1] = ((const float4*)fp)[1];
  ((float4*)fv)[2] = ((const float4*)fp)[2];
  ((float4*)fv)[3] = ((const float4*)fp)[3];
  const float scale = (h < NH) ? QSCALE : 1.0f;
  ushort_t obuf[16];
#pragma unroll
  for (int i = 0; i < 8; ++i) {
    float x0 = xv[2 * i], x1 = xv[2 * i + 1];
    float cs = fv[2 * i], sn = fv[2 * i + 1];
    obuf[2 * i]     = f2b((x0 * cs - x1 * sn) * scale);
    obuf[2 * i + 1] = f2b((x1 * cs + x0 * sn) * scale);
  }
  ushort_t* dst;
  if (h < NH) dst = Qb + ((size_t)s * NH + h) * 64 + part * 16;
  else        dst = Kb + ((size_t)s * NKV + (h - NH)) * 64 + part * 16;
  *(s8v*)dst = *(const s8v*)&obuf[0];
  *(s8v*)(dst + 8) = *(const s8v*)&obuf[8];
}

// ---------------- V transpose: qkvF[s][2560+hd] (f32) -> Vt[hd][s] (bf16) ----------------
__global__ void transp_v(const float* __restrict__ qkvF, ushort_t* __restrict__ Vt) {
  __shared__ float t[32][33];
  int hd0 = blockIdx.x * 32, s0 = blockIdx.y * 32;
#pragma unroll
  for (int k = 0; k < 4; ++k) {
    int sy = threadIdx.y + k * 8;
    t[sy][threadIdx.x] = qkvF[(size_t)(s0 + sy) * DQKV + 2560 + hd0 + threadIdx.x];
  }
  __syncthreads();
#pragma unroll
  for (int k = 0; k < 4; ++k) {
    int hy = threadIdx.y + k * 8;
    Vt[(size_t)(hd0 + hy) * S_LEN + s0 + threadIdx.x] = f2b(t[threadIdx.x][hy]);
  }
}

// ---------------- softmax step for one accumulator (in-register, exp2 domain) ----------------
__device__ __forceinline__ void softmax_pack(f4v (&sc)[4], float& m, float& l,
                                             f4v (&y)[4], s8v (&pf)[2], int fg) {
  float pmax = sc[0][0];
#pragma unroll
  for (int n = 0; n < 4; ++n)
#pragma unroll
    for (int r = 0; r < 4; ++r) pmax = fmaxf(pmax, sc[n][r]);
  pmax = fmaxf(pmax, __shfl_xor(pmax, 16));
  pmax = fmaxf(pmax, __shfl_xor(pmax, 32));
  if (!__all(pmax <= m + 8.f)) {            // defer-max (T13), wave-uniform
    float mn = fmaxf(m, pmax);
    float al = exp2f(m - mn);
    m = mn;
    l *= al;
    float aly[4];
#pragma unroll
    for (int rr = 0; rr < 4; ++rr) aly[rr] = __shfl(al, fg * 4 + rr);
#pragma unroll
    for (int d = 0; d < 4; ++d)
#pragma unroll
      for (int rr = 0; rr < 4; ++rr) y[d][rr] *= aly[rr];
  }
  float rs = 0.f;
#pragma unroll
  for (int n = 0; n < 4; ++n)
#pragma unroll
    for (int r = 0; r < 4; ++r) {
      float p = exp2f(sc[n][r] - m);
      sc[n][r] = p;
      rs += p;
    }
  l += rs;                                   // per-lane partial; reduced at finalize
#pragma unroll
  for (int c = 0; c < 2; ++c) {
    unsigned wb[4];
    wb[0] = cvtpk(sc[2 * c][0], sc[2 * c][1]);
    wb[1] = cvtpk(sc[2 * c][2], sc[2 * c][3]);
    wb[2] = cvtpk(sc[2 * c + 1][0], sc[2 * c + 1][1]);
    wb[3] = cvtpk(sc[2 * c + 1][2], sc[2 * c + 1][3]);
    pf[c] = *(const s8v*)&wb[0];
  }
}

__device__ __forceinline__ void finalize_y(f4v (&y)[4], float l, int q0, int head,
                                           int fr, int fg, ushort_t* __restrict__ Y) {
  l += __shfl_xor(l, 16);
  l += __shfl_xor(l, 32);
  float linv[4];
#pragma unroll
  for (int rr = 0; rr < 4; ++rr) linv[rr] = 1.f / __shfl(l, fg * 4 + rr);
#pragma unroll
  for (int d = 0; d < 4; ++d)
#pragma unroll
    for (int rr = 0; rr < 4; ++rr)
      Y[(size_t)(q0 + fg * 4 + rr) * HID + head * 64 + d * 16 + fr] =
          f2b(y[d][rr] * linv[rr]);
}

// ---------------- causal GQA flash attention, paired q-tiles ----------------
// 1 wave/block; block bx pairs q-tiles jA=127-bx (long) and jB=bx (short) of the
// same head: one shared K/V stream, two independent accumulators (2x ILP, K/V
// loads amortized while both active). Swapped QK^T + permuted K rows keep P
// lane-local for PV (no LDS). Softmax in exp2 domain, per-lane partial l.
__global__ __launch_bounds__(64) void attn(
    const ushort_t* __restrict__ Q, const ushort_t* __restrict__ Kc,
    const ushort_t* __restrict__ Vt, ushort_t* __restrict__ Y) {
  const int head = blockIdx.y, kvh = head >> 2;
  const int lane = threadIdx.x;
  const int fr = lane & 15, fg = lane >> 4;
  const int jA = 127 - (int)blockIdx.x;     // long q-tile
  const int jB = (int)blockIdx.x;           // short q-tile
  const int q0A = jA * 16, q0B = jB * 16;
  const int ntA = (q0A >> 6) + 1, ntB = (q0B >> 6) + 1;

  s8v qfA[2], qfB[2];
#pragma unroll
  for (int c = 0; c < 2; ++c) {
    qfA[c] = *(const s8v*)(Q + ((size_t)(q0A + fr) * NH + head) * 64 + c * 32 + fg * 8);
    qfB[c] = *(const s8v*)(Q + ((size_t)(q0B + fr) * NH + head) * 64 + c * 32 + fg * 8);
  }

  float mA = -3.0e38f, lA = 0.f, mB = -3.0e38f, lB = 0.f;
  f4v yA[4], yB[4];
#pragma unroll
  for (int d = 0; d < 4; ++d) {
    yA[d] = (f4v){0.f, 0.f, 0.f, 0.f};
    yB[d] = (f4v){0.f, 0.f, 0.f, 0.f};
  }

  for (int t = 0; t < ntA; ++t) {
    const int kv0 = t * 64;
    const bool doB = (t < ntB);             // wave-uniform
    // ---- shared K fragments (permuted rows -> P lands lane-local) ----
    s8v kf[4][2];
#pragma unroll
    for (int n = 0; n < 4; ++n) {
      const int krow = kv0 + 32 * (n >> 1) + 8 * (fr >> 2) + 4 * (n & 1) + (fr & 3);
      const ushort_t* kb = Kc + ((size_t)krow * NKV + kvh) * 64 + fg * 8;
      kf[n][0] = *(const s8v*)kb;
      kf[n][1] = *(const s8v*)(kb + 32);
    }
    // ---- S^T[kv][q] for both q-tiles ----
    f4v scA[4], scB[4];
#pragma unroll
    for (int n = 0; n < 4; ++n) {
      f4v a = (f4v){0.f, 0.f, 0.f, 0.f};
      a = __builtin_amdgcn_mfma_f32_16x16x32_bf16(kf[n][0], qfA[0], a, 0, 0, 0);
      a = __builtin_amdgcn_mfma_f32_16x16x32_bf16(kf[n][1], qfA[1], a, 0, 0, 0);
      scA[n] = a;
    }
    if (doB) {
#pragma unroll
      for (int n = 0; n < 4; ++n) {
        f4v a = (f4v){0.f, 0.f, 0.f, 0.f};
        a = __builtin_amdgcn_mfma_f32_16x16x32_bf16(kf[n][0], qfB[0], a, 0, 0, 0);
        a = __builtin_amdgcn_mfma_f32_16x16x32_bf16(kf[n][1], qfB[1], a, 0, 0, 0);
        scB[n] = a;
      }
    }
    // ---- causal masks (permuted kv index) ----
    if (t == ntA - 1) {
#pragma unroll
      for (int n = 0; n < 4; ++n)
#pragma unroll
        for (int r = 0; r < 4; ++r) {
          int kv = kv0 + 32 * (n >> 1) + 8 * fg + 4 * (n & 1) + r;
          if (kv > q0A + fr) scA[n][r] = -1e30f;
        }
    }
    if (doB && t == ntB - 1) {
#pragma unroll
      for (int n = 0; n < 4; ++n)
#pragma unroll
        for (int r = 0; r < 4; ++r) {
          int kv = kv0 + 32 * (n >> 1) + 8 * fg + 4 * (n & 1) + r;
          if (kv > q0B + fr) scB[n][r] = -1e30f;
        }
    }
    // ---- softmax + pack ----
    s8v pfA[2], pfB[2];
    softmax_pack(scA, mA, lA, yA, pfA, fg);
    if (doB) softmax_pack(scB, mB, lB, yB, pfB, fg);
    // ---- PV with shared V fragments ----
#pragma unroll
    for (int d = 0; d < 4; ++d) {
      const ushort_t* vb = Vt + ((size_t)(kvh * 64 + d * 16 + fr)) * S_LEN + kv0 + fg * 8;
      s8v vf0 = *(const s8v*)vb;
      s8v vf1 = *(const s8v*)(vb + 32);
      yA[d] = __builtin_amdgcn_mfma_f32_16x16x32_bf16(pfA[0], vf0, yA[d], 0, 0, 0);
      yA[d] = __builtin_amdgcn_mfma_f32_16x16x32_bf16(pfA[1], vf1, yA[d], 0, 0, 0);
      if (doB) {
        yB[d] = __builtin_amdgcn_mfma_f32_16x16x32_bf16(pfB[0], vf0, yB[d], 0, 0, 0);
        yB[d] = __builtin_amdgcn_mfma_f32_16x16x32_bf16(pfB[1], vf1, yB[d], 0, 0, 0);
      }
    }
  }
  finalize_y(yA, lA, q0A, head, fr, fg, Y);
  finalize_y(yB, lB, q0B, head, fr, fg, Y);
}

// ---------------- launch ----------------
extern "C" void kernel_launch(void* const* d_in, const int* in_sizes, int n_in,
                              void* d_out, int out_size, void* d_ws, size_t ws_size,
                              hipStream_t stream) {
  const float* x    = (const float*)d_in[0];
  const float* fc   = (const float*)d_in[1];
  const float* wqkv = (const float*)d_in[3];
  const float* wo   = (const float*)d_in[4];
  float* out = (float*)d_out;

  char* ws = (char*)d_ws;
  ushort_t* xb    = (ushort_t*)(ws);               // 8 MB; reused as Y after attn
  ushort_t* wqkvb = (ushort_t*)(ws + 8388608);     // 12 MB; dead after GEMM1:
  ushort_t* Qb    = (ushort_t*)(ws + 8388608);     //   Q (8 MB) aliases it
  ushort_t* Kb    = (ushort_t*)(ws + 16777216);    //   K (2 MB)
  ushort_t* Vtb   = (ushort_t*)(ws + 18874368);    //   Vt (2 MB)
  ushort_t* wob   = (ushort_t*)(ws + 20971520);    // 8 MB
  float*    qkvF  = (float*)(ws + 29360128);       // 25.17 MB f32 (split-K target)
  ushort_t* Yb    = xb;

  hipMemsetAsync(qkvF, 0, 25165824, stream);
  hipMemsetAsync(out, 0, 16777216, stream);

  cvt3<<<14336, 256, 0, stream>>>(x, wqkv, wo, xb, wqkvb, wob);

  gemm_bt_sk<<<dim3(24, 16, 2), 256, 0, stream>>>(xb, wqkvb, qkvF, 2048, 3072, 2048);

  rope_qk<<<1280, 256, 0, stream>>>(qkvF, fc, Qb, Kb);
  transp_v<<<dim3(16, 64), dim3(32, 8), 0, stream>>>(qkvF, Vtb);

  attn<<<dim3(64, 32), 64, 0, stream>>>(Qb, Kb, Vtb, Yb);

  gemm_bt_sk<<<dim3(16, 16, 2), 256, 0, stream>>>(Yb, wob, out, 2048, 2048, 2048);
}

// Round 8
// 309.865 us; speedup vs baseline: 1.1731x; 1.1731x over previous
//
#include <hip/hip_runtime.h>
#include <stdint.h>

typedef unsigned short ushort_t;
typedef __attribute__((ext_vector_type(8))) short s8v;
typedef __attribute__((ext_vector_type(4))) float f4v;

#define NH 32
#define NKV 8
#define HD 64
#define S_LEN 2048
#define HID 2048
#define DQKV 3072

// 0.125 (HD^-0.5) * log2(e): softmax runs in exp2 domain
#define QSCALE 0.18033688011112042f

__device__ __forceinline__ ushort_t f2b(float f) {
  union { float f; unsigned u; } v; v.f = f;
  unsigned r = v.u + 0x7FFFu + ((v.u >> 16) & 1u);
  return (ushort_t)(r >> 16);
}
__device__ __forceinline__ float b2f(ushort_t h) {
  union { unsigned u; float f; } v; v.u = ((unsigned)h) << 16;
  return v.f;
}
__device__ __forceinline__ unsigned cvtpk(float lo, float hi) {
  unsigned r;
  asm("v_cvt_pk_bf16_f32 %0, %1, %2" : "=v"(r) : "v"(lo), "v"(hi));
  return r;
}

// ---------------- fused f32 -> bf16 convert for x, Wqkv, Wo ----------------
__global__ void cvt3(const float* __restrict__ a, const float* __restrict__ b,
                     const float* __restrict__ c, ushort_t* __restrict__ oa,
                     ushort_t* __restrict__ ob, ushort_t* __restrict__ oc) {
  const int n1 = 1048576, n2 = 1572864;  // x/4, wqkv/4 (wo/4 = n1)
  int i = blockIdx.x * blockDim.x + threadIdx.x;
  const float* in; ushort_t* out; int j;
  if (i < n1) { in = a; out = oa; j = i; }
  else if (i < n1 + n2) { in = b; out = ob; j = i - n1; }
  else { in = c; out = oc; j = i - n1 - n2; }
  float4 v = ((const float4*)in)[j];
  uint2 p;
  p.x = cvtpk(v.x, v.y);
  p.y = cvtpk(v.z, v.w);
  ((uint2*)out)[j] = p;
}

// ---------------- split-K GEMM: partial C = A[.,Khalf] * B[.,Khalf]^T (bf16 out) ----------------
// 128x128 tile, BK=32, 4 waves; blockIdx.z selects K half and partial buffer.
// No atomics: each z writes its own bf16 partial; consumer adds them.
__global__ __launch_bounds__(256) void gemm_bt_sk(
    const ushort_t* __restrict__ A, const ushort_t* __restrict__ B,
    ushort_t* __restrict__ C0, ushort_t* __restrict__ C1, int M, int N, int K) {
  __shared__ ushort_t sA[128 * 32];
  __shared__ ushort_t sB[128 * 32];
  const int tid = threadIdx.x;
  const int wave = tid >> 6, lane = tid & 63;
  const int bm = blockIdx.y * 128, bn = blockIdx.x * 128;
  const int wm = (wave >> 1) * 64, wn = (wave & 1) * 64;
  const int srow = wave * 16 + (lane >> 2);
  const int scol = (lane & 3) * 8;
  const int fr = lane & 15, fg = lane >> 4;
  const int khalf = K >> 1;
  const int kbeg = blockIdx.z * khalf;
  ushort_t* C = blockIdx.z ? C1 : C0;

  f4v acc[4][4];
#pragma unroll
  for (int m = 0; m < 4; ++m)
#pragma unroll
    for (int n = 0; n < 4; ++n) acc[m][n] = (f4v){0.f, 0.f, 0.f, 0.f};

  for (int k0 = kbeg; k0 < kbeg + khalf; k0 += 32) {
    __syncthreads();
#pragma unroll
    for (int it = 0; it < 2; ++it) {
      int r = it * 64 + srow;
      __builtin_amdgcn_global_load_lds(
          (const __attribute__((address_space(1))) void*)(A + (size_t)(bm + r) * K + k0 + scol),
          (__attribute__((address_space(3))) void*)(&sA[(it * 64 + wave * 16) * 32]),
          16, 0, 0);
      __builtin_amdgcn_global_load_lds(
          (const __attribute__((address_space(1))) void*)(B + (size_t)(bn + r) * K + k0 + scol),
          (__attribute__((address_space(3))) void*)(&sB[(it * 64 + wave * 16) * 32]),
          16, 0, 0);
    }
    __syncthreads();

    s8v af[4], bf[4];
#pragma unroll
    for (int m = 0; m < 4; ++m)
      af[m] = *(const s8v*)&sA[(wm + m * 16 + fr) * 32 + fg * 8];
#pragma unroll
    for (int n = 0; n < 4; ++n)
      bf[n] = *(const s8v*)&sB[(wn + n * 16 + fr) * 32 + fg * 8];
#pragma unroll
    for (int m = 0; m < 4; ++m)
#pragma unroll
      for (int n = 0; n < 4; ++n)
        acc[m][n] = __builtin_amdgcn_mfma_f32_16x16x32_bf16(af[m], bf[n], acc[m][n], 0, 0, 0);
  }

#pragma unroll
  for (int m = 0; m < 4; ++m)
#pragma unroll
    for (int n = 0; n < 4; ++n)
#pragma unroll
      for (int rr = 0; rr < 4; ++rr) {
        int row = bm + wm + m * 16 + fg * 4 + rr;
        int col = bn + wn + n * 16 + fr;
        C[(size_t)row * N + col] = f2b(acc[m][n][rr]);
      }
}

// ---------------- add2: out[i] = P0[i] + P1[i] (bf16 partials -> f32 out) ----------------
__global__ void add2(const ushort_t* __restrict__ a, const ushort_t* __restrict__ b,
                     float* __restrict__ out) {
  int i = blockIdx.x * blockDim.x + threadIdx.x;  // 1M quads of 4
  uint2 pa = ((const uint2*)a)[i];
  uint2 pb = ((const uint2*)b)[i];
  float4 o;
  o.x = b2f((ushort_t)(pa.x & 0xFFFF)) + b2f((ushort_t)(pb.x & 0xFFFF));
  o.y = b2f((ushort_t)(pa.x >> 16))    + b2f((ushort_t)(pb.x >> 16));
  o.z = b2f((ushort_t)(pa.y & 0xFFFF)) + b2f((ushort_t)(pb.y & 0xFFFF));
  o.w = b2f((ushort_t)(pa.y >> 16))    + b2f((ushort_t)(pb.y >> 16));
  ((float4*)out)[i] = o;
}

// ---------------- RoPE on q,k (sums bf16 qkv partials, writes bf16 Q,K) ----------------
__global__ void rope_qk(const ushort_t* __restrict__ P0, const ushort_t* __restrict__ P1,
                        const float* __restrict__ fc,
                        ushort_t* __restrict__ Qb, ushort_t* __restrict__ Kb) {
  int tid = blockIdx.x * blockDim.x + threadIdx.x;
  if (tid >= S_LEN * 160) return;           // (NH+NKV) heads * 4 parts of 16
  int s = tid / 160, c = tid - s * 160;
  int h = c >> 2, part = c & 3;
  size_t off = (size_t)s * DQKV + h * 64 + part * 16;
  s8v a0 = *(const s8v*)(P0 + off);
  s8v a1 = *(const s8v*)(P0 + off + 8);
  s8v b0 = *(const s8v*)(P1 + off);
  s8v b1 = *(const s8v*)(P1 + off + 8);
  float xv[16];
#pragma unroll
  for (int i = 0; i < 8; ++i) {
    xv[i]     = b2f((ushort_t)a0[i]) + b2f((ushort_t)b0[i]);
    xv[8 + i] = b2f((ushort_t)a1[i]) + b2f((ushort_t)b1[i]);
  }
  const float* fp = fc + s * 64 + part * 16;
  float fv[16];
  ((float4*)fv)[0] = ((const float4*)fp)[0];
  ((float4*)fv)[1] = ((const float4*)fp)[1];
  ((float4*)fv)[2] = ((const float4*)fp)[2];
  ((float4*)fv)[3] = ((const float4*)fp)[3];
  const float scale = (h < NH) ? QSCALE : 1.0f;
  ushort_t obuf[16];
#pragma unroll
  for (int i = 0; i < 8; ++i) {
    float x0 = xv[2 * i], x1 = xv[2 * i + 1];
    float cs = fv[2 * i], sn = fv[2 * i + 1];
    obuf[2 * i]     = f2b((x0 * cs - x1 * sn) * scale);
    obuf[2 * i + 1] = f2b((x1 * cs + x0 * sn) * scale);
  }
  ushort_t* dst;
  if (h < NH) dst = Qb + ((size_t)s * NH + h) * 64 + part * 16;
  else        dst = Kb + ((size_t)s * NKV + (h - NH)) * 64 + part * 16;
  *(s8v*)dst = *(const s8v*)&obuf[0];
  *(s8v*)(dst + 8) = *(const s8v*)&obuf[8];
}

// ---------------- V transpose: partial-sum qkv[s][2560+hd] -> Vt[hd][s] (bf16) ----------------
__global__ void transp_v(const ushort_t* __restrict__ P0, const ushort_t* __restrict__ P1,
                         ushort_t* __restrict__ Vt) {
  __shared__ float t[32][33];
  int hd0 = blockIdx.x * 32, s0 = blockIdx.y * 32;
#pragma unroll
  for (int k = 0; k < 4; ++k) {
    int sy = threadIdx.y + k * 8;
    size_t off = (size_t)(s0 + sy) * DQKV + 2560 + hd0 + threadIdx.x;
    t[sy][threadIdx.x] = b2f(P0[off]) + b2f(P1[off]);
  }
  __syncthreads();
#pragma unroll
  for (int k = 0; k < 4; ++k) {
    int hy = threadIdx.y + k * 8;
    Vt[(size_t)(hd0 + hy) * S_LEN + s0 + threadIdx.x] = f2b(t[threadIdx.x][hy]);
  }
}

// ---------------- softmax step for one accumulator (in-register, exp2 domain) ----------------
__device__ __forceinline__ void softmax_pack(f4v (&sc)[4], float& m, float& l,
                                             f4v (&y)[4], s8v (&pf)[2], int fg) {
  float pmax = sc[0][0];
#pragma unroll
  for (int n = 0; n < 4; ++n)
#pragma unroll
    for (int r = 0; r < 4; ++r) pmax = fmaxf(pmax, sc[n][r]);
  pmax = fmaxf(pmax, __shfl_xor(pmax, 16));
  pmax = fmaxf(pmax, __shfl_xor(pmax, 32));
  if (!__all(pmax <= m + 8.f)) {            // defer-max (T13), wave-uniform
    float mn = fmaxf(m, pmax);
    float al = exp2f(m - mn);
    m = mn;
    l *= al;
    float aly[4];
#pragma unroll
    for (int rr = 0; rr < 4; ++rr) aly[rr] = __shfl(al, fg * 4 + rr);
#pragma unroll
    for (int d = 0; d < 4; ++d)
#pragma unroll
      for (int rr = 0; rr < 4; ++rr) y[d][rr] *= aly[rr];
  }
  float rs = 0.f;
#pragma unroll
  for (int n = 0; n < 4; ++n)
#pragma unroll
    for (int r = 0; r < 4; ++r) {
      float p = exp2f(sc[n][r] - m);
      sc[n][r] = p;
      rs += p;
    }
  l += rs;                                   // per-lane partial; reduced at finalize
#pragma unroll
  for (int c = 0; c < 2; ++c) {
    unsigned wb[4];
    wb[0] = cvtpk(sc[2 * c][0], sc[2 * c][1]);
    wb[1] = cvtpk(sc[2 * c][2], sc[2 * c][3]);
    wb[2] = cvtpk(sc[2 * c + 1][0], sc[2 * c + 1][1]);
    wb[3] = cvtpk(sc[2 * c + 1][2], sc[2 * c + 1][3]);
    pf[c] = *(const s8v*)&wb[0];
  }
}

__device__ __forceinline__ void finalize_y(f4v (&y)[4], float l, int q0, int head,
                                           int fr, int fg, ushort_t* __restrict__ Y) {
  l += __shfl_xor(l, 16);
  l += __shfl_xor(l, 32);
  float linv[4];
#pragma unroll
  for (int rr = 0; rr < 4; ++rr) linv[rr] = 1.f / __shfl(l, fg * 4 + rr);
#pragma unroll
  for (int d = 0; d < 4; ++d)
#pragma unroll
    for (int rr = 0; rr < 4; ++rr)
      Y[(size_t)(q0 + fg * 4 + rr) * HID + head * 64 + d * 16 + fr] =
          f2b(y[d][rr] * linv[rr]);
}

// ---------------- causal GQA flash attention: paired q-tiles + 2-wave kv-split ----------------
// Block bx: q-tiles jA=127-bx (long) and jB=bx (short) of head by.
// 2 waves split the kv-tile stream (t = w, w+2, ...), each keeping its own
// online-softmax state; states merged once at the end via padded LDS exchange
// (wave0 merges+writes tile A, wave1 tile B). 4096 waves total = 16 waves/CU.
__global__ __launch_bounds__(128) void attn(
    const ushort_t* __restrict__ Q, const ushort_t* __restrict__ Kc,
    const ushort_t* __restrict__ Vt, ushort_t* __restrict__ Y) {
  __shared__ float Lm[2][64];
  __shared__ float Ll[2][64];
  __shared__ float Ly[2][64][17];           // +1 pad: stride 17 -> conflict-free
  const int head = blockIdx.y, kvh = head >> 2;
  const int w = threadIdx.x >> 6;           // wave id 0/1
  const int lane = threadIdx.x & 63;
  const int fr = lane & 15, fg = lane >> 4;
  const int jA = 127 - (int)blockIdx.x;     // long q-tile
  const int jB = (int)blockIdx.x;           // short q-tile
  const int q0A = jA * 16, q0B = jB * 16;
  const int ntA = (q0A >> 6) + 1, ntB = (q0B >> 6) + 1;

  s8v qfA[2], qfB[2];
#pragma unroll
  for (int c = 0; c < 2; ++c) {
    qfA[c] = *(const s8v*)(Q + ((size_t)(q0A + fr) * NH + head) * 64 + c * 32 + fg * 8);
    qfB[c] = *(const s8v*)(Q + ((size_t)(q0B + fr) * NH + head) * 64 + c * 32 + fg * 8);
  }

  float mA = -3.0e38f, lA = 0.f, mB = -3.0e38f, lB = 0.f;
  f4v yA[4], yB[4];
#pragma unroll
  for (int d = 0; d < 4; ++d) {
    yA[d] = (f4v){0.f, 0.f, 0.f, 0.f};
    yB[d] = (f4v){0.f, 0.f, 0.f, 0.f};
  }

  for (int t = w; t < ntA; t += 2) {
    const int kv0 = t * 64;
    const bool doB = (t < ntB);             // wave-uniform
    // ---- shared K fragments (permuted rows -> P lands lane-local) ----
    s8v kf[4][2];
#pragma unroll
    for (int n = 0; n < 4; ++n) {
      const int krow = kv0 + 32 * (n >> 1) + 8 * (fr >> 2) + 4 * (n & 1) + (fr & 3);
      const ushort_t* kb = Kc + ((size_t)krow * NKV + kvh) * 64 + fg * 8;
      kf[n][0] = *(const s8v*)kb;
      kf[n][1] = *(const s8v*)(kb + 32);
    }
    // ---- S^T[kv][q] for both q-tiles ----
    f4v scA[4], scB[4];
#pragma unroll
    for (int n = 0; n < 4; ++n) {
      f4v a = (f4v){0.f, 0.f, 0.f, 0.f};
      a = __builtin_amdgcn_mfma_f32_16x16x32_bf16(kf[n][0], qfA[0], a, 0, 0, 0);
      a = __builtin_amdgcn_mfma_f32_16x16x32_bf16(kf[n][1], qfA[1], a, 0, 0, 0);
      scA[n] = a;
    }
    if (doB) {
#pragma unroll
      for (int n = 0; n < 4; ++n) {
        f4v a = (f4v){0.f, 0.f, 0.f, 0.f};
        a = __builtin_amdgcn_mfma_f32_16x16x32_bf16(kf[n][0], qfB[0], a, 0, 0, 0);
        a = __builtin_amdgcn_mfma_f32_16x16x32_bf16(kf[n][1], qfB[1], a, 0, 0, 0);
        scB[n] = a;
      }
    }
    // ---- causal masks (permuted kv index) ----
    if (t == ntA - 1) {
#pragma unroll
      for (int n = 0; n < 4; ++n)
#pragma unroll
        for (int r = 0; r < 4; ++r) {
          int kv = kv0 + 32 * (n >> 1) + 8 * fg + 4 * (n & 1) + r;
          if (kv > q0A + fr) scA[n][r] = -1e30f;
        }
    }
    if (doB && t == ntB - 1) {
#pragma unroll
      for (int n = 0; n < 4; ++n)
#pragma unroll
        for (int r = 0; r < 4; ++r) {
          int kv = kv0 + 32 * (n >> 1) + 8 * fg + 4 * (n & 1) + r;
          if (kv > q0B + fr) scB[n][r] = -1e30f;
        }
    }
    // ---- softmax + pack ----
    s8v pfA[2], pfB[2];
    softmax_pack(scA, mA, lA, yA, pfA, fg);
    if (doB) softmax_pack(scB, mB, lB, yB, pfB, fg);
    // ---- PV with shared V fragments ----
#pragma unroll
    for (int d = 0; d < 4; ++d) {
      const ushort_t* vb = Vt + ((size_t)(kvh * 64 + d * 16 + fr)) * S_LEN + kv0 + fg * 8;
      s8v vf0 = *(const s8v*)vb;
      s8v vf1 = *(const s8v*)(vb + 32);
      yA[d] = __builtin_amdgcn_mfma_f32_16x16x32_bf16(pfA[0], vf0, yA[d], 0, 0, 0);
      yA[d] = __builtin_amdgcn_mfma_f32_16x16x32_bf16(pfA[1], vf1, yA[d], 0, 0, 0);
      if (doB) {
        yB[d] = __builtin_amdgcn_mfma_f32_16x16x32_bf16(pfB[0], vf0, yB[d], 0, 0, 0);
        yB[d] = __builtin_amdgcn_mfma_f32_16x16x32_bf16(pfB[1], vf1, yB[d], 0, 0, 0);
      }
    }
  }

  // ---- cross-wave merge: wave0 stores B-state, wave1 stores A-state ----
  if (w == 0) {
    Lm[1][lane] = mB; Ll[1][lane] = lB;
#pragma unroll
    for (int d = 0; d < 4; ++d)
#pragma unroll
      for (int rr = 0; rr < 4; ++rr) Ly[1][lane][d * 4 + rr] = yB[d][rr];
  } else {
    Lm[0][lane] = mA; Ll[0][lane] = lA;
#pragma unroll
    for (int d = 0; d < 4; ++d)
#pragma unroll
      for (int rr = 0; rr < 4; ++rr) Ly[0][lane][d * 4 + rr] = yA[d][rr];
  }
  __syncthreads();
  if (w == 0) {
    // merge A (own regs + wave1's LDS state), finalize
    float m1 = Lm[0][lane], l1 = Ll[0][lane];
    float mm = fmaxf(mA, m1);
    float s0 = exp2f(mA - mm), s1 = exp2f(m1 - mm);
    float lm = lA * s0 + l1 * s1;
    float s0y[4], s1y[4];
#pragma unroll
    for (int rr = 0; rr < 4; ++rr) {
      s0y[rr] = __shfl(s0, fg * 4 + rr);
      s1y[rr] = __shfl(s1, fg * 4 + rr);
    }
#pragma unroll
    for (int d = 0; d < 4; ++d)
#pragma unroll
      for (int rr = 0; rr < 4; ++rr)
        yA[d][rr] = yA[d][rr] * s0y[rr] + Ly[0][lane][d * 4 + rr] * s1y[rr];
    finalize_y(yA, lm, q0A, head, fr, fg, Y);
  } else {
    float m1 = Lm[1][lane], l1 = Ll[1][lane];
    float mm = fmaxf(mB, m1);
    float s0 = exp2f(mB - mm), s1 = exp2f(m1 - mm);
    float lm = lB * s0 + l1 * s1;
    float s0y[4], s1y[4];
#pragma unroll
    for (int rr = 0; rr < 4; ++rr) {
      s0y[rr] = __shfl(s0, fg * 4 + rr);
      s1y[rr] = __shfl(s1, fg * 4 + rr);
    }
#pragma unroll
    for (int d = 0; d < 4; ++d)
#pragma unroll
      for (int rr = 0; rr < 4; ++rr)
        yB[d][rr] = yB[d][rr] * s0y[rr] + Ly[1][lane][d * 4 + rr] * s1y[rr];
    finalize_y(yB, lm, q0B, head, fr, fg, Y);
  }
}

// ---------------- launch ----------------
extern "C" void kernel_launch(void* const* d_in, const int* in_sizes, int n_in,
                              void* d_out, int out_size, void* d_ws, size_t ws_size,
                              hipStream_t stream) {
  const float* x    = (const float*)d_in[0];
  const float* fc   = (const float*)d_in[1];
  const float* wqkv = (const float*)d_in[3];
  const float* wo   = (const float*)d_in[4];
  float* out = (float*)d_out;

  char* ws = (char*)d_ws;
  ushort_t* xb    = (ushort_t*)(ws);               // 8 MB; reused as Y after attn
  ushort_t* wqkvb = (ushort_t*)(ws + 8388608);     // 12 MB; dead after GEMM1:
  ushort_t* Qb    = (ushort_t*)(ws + 8388608);     //   Q (8 MB) aliases it
  ushort_t* Kb    = (ushort_t*)(ws + 16777216);    //   K (2 MB)
  ushort_t* Vtb   = (ushort_t*)(ws + 18874368);    //   Vt (2 MB)
  ushort_t* wob   = (ushort_t*)(ws + 20971520);    // 8 MB -> ends 28 MiB
  ushort_t* P0    = (ushort_t*)(ws + 29360128);    // 12 MiB qkv partial (z=0)
  ushort_t* P1    = (ushort_t*)(ws + 41943040);    // 12 MiB qkv partial (z=1) -> 52 MiB
  ushort_t* G0    = (ushort_t*)(ws + 29360128);    // 8 MiB out partial (aliases P0, dead)
  ushort_t* G1    = (ushort_t*)(ws + 37748736);    // 8 MiB out partial
  ushort_t* Yb    = xb;

  cvt3<<<14336, 256, 0, stream>>>(x, wqkv, wo, xb, wqkvb, wob);

  gemm_bt_sk<<<dim3(24, 16, 2), 256, 0, stream>>>(xb, wqkvb, P0, P1, 2048, 3072, 2048);

  rope_qk<<<1280, 256, 0, stream>>>(P0, P1, fc, Qb, Kb);
  transp_v<<<dim3(16, 64), dim3(32, 8), 0, stream>>>(P0, P1, Vtb);

  attn<<<dim3(64, 32), 128, 0, stream>>>(Qb, Kb, Vtb, Yb);

  gemm_bt_sk<<<dim3(16, 16, 2), 256, 0, stream>>>(Yb, wob, G0, G1, 2048, 2048, 2048);

  add2<<<4096, 256, 0, stream>>>(G0, G1, out);
}

// Round 11
// 273.555 us; speedup vs baseline: 1.3288x; 1.1327x over previous
//
#include <hip/hip_runtime.h>
#include <stdint.h>

typedef unsigned short ushort_t;
typedef __attribute__((ext_vector_type(8))) short s8v;
typedef __attribute__((ext_vector_type(4))) float f4v;

#define NH 32
#define NKV 8
#define HD 64
#define S_LEN 2048
#define HID 2048
#define DQKV 3072

// packed K/V strides (bf16 elems): per-(n|d,c) chunk 512, per kv-tile 4096, per kvh 131072
#define PK_CHUNK 512
#define PK_TILE 4096
#define PK_HEAD 131072

// 0.125 (HD^-0.5) * log2(e): softmax runs in exp2 domain
#define QSCALE 0.18033688011112042f

__device__ __forceinline__ ushort_t f2b(float f) {
  union { float f; unsigned u; } v; v.f = f;
  unsigned r = v.u + 0x7FFFu + ((v.u >> 16) & 1u);
  return (ushort_t)(r >> 16);
}
__device__ __forceinline__ float b2f(ushort_t h) {
  union { unsigned u; float f; } v; v.u = ((unsigned)h) << 16;
  return v.f;
}
__device__ __forceinline__ unsigned cvtpk(float lo, float hi) {
  unsigned r;
  asm("v_cvt_pk_bf16_f32 %0, %1, %2" : "=v"(r) : "v"(lo), "v"(hi));
  return r;
}

// ---------------- fused f32 -> bf16 convert for x, Wqkv, Wo ----------------
__global__ void cvt3(const float* __restrict__ a, const float* __restrict__ b,
                     const float* __restrict__ c, ushort_t* __restrict__ oa,
                     ushort_t* __restrict__ ob, ushort_t* __restrict__ oc) {
  const int n1 = 1048576, n2 = 1572864;  // x/4, wqkv/4 (wo/4 = n1)
  int i = blockIdx.x * blockDim.x + threadIdx.x;
  const float* in; ushort_t* out; int j;
  if (i < n1) { in = a; out = oa; j = i; }
  else if (i < n1 + n2) { in = b; out = ob; j = i - n1; }
  else { in = c; out = oc; j = i - n1 - n2; }
  float4 v = ((const float4*)in)[j];
  uint2 p;
  p.x = cvtpk(v.x, v.y);
  p.y = cvtpk(v.z, v.w);
  ((uint2*)out)[j] = p;
}

// ---------------- split-K GEMM: partial C = A[.,Khalf] * B[.,Khalf]^T (bf16 out) ----------------
__global__ __launch_bounds__(256) void gemm_bt_sk(
    const ushort_t* __restrict__ A, const ushort_t* __restrict__ B,
    ushort_t* __restrict__ C0, ushort_t* __restrict__ C1, int M, int N, int K) {
  __shared__ ushort_t sA[128 * 32];
  __shared__ ushort_t sB[128 * 32];
  const int tid = threadIdx.x;
  const int wave = tid >> 6, lane = tid & 63;
  const int bm = blockIdx.y * 128, bn = blockIdx.x * 128;
  const int wm = (wave >> 1) * 64, wn = (wave & 1) * 64;
  const int srow = wave * 16 + (lane >> 2);
  const int scol = (lane & 3) * 8;
  const int fr = lane & 15, fg = lane >> 4;
  const int khalf = K >> 1;
  const int kbeg = blockIdx.z * khalf;
  ushort_t* C = blockIdx.z ? C1 : C0;

  f4v acc[4][4];
#pragma unroll
  for (int m = 0; m < 4; ++m)
#pragma unroll
    for (int n = 0; n < 4; ++n) acc[m][n] = (f4v){0.f, 0.f, 0.f, 0.f};

  for (int k0 = kbeg; k0 < kbeg + khalf; k0 += 32) {
    __syncthreads();
#pragma unroll
    for (int it = 0; it < 2; ++it) {
      int r = it * 64 + srow;
      __builtin_amdgcn_global_load_lds(
          (const __attribute__((address_space(1))) void*)(A + (size_t)(bm + r) * K + k0 + scol),
          (__attribute__((address_space(3))) void*)(&sA[(it * 64 + wave * 16) * 32]),
          16, 0, 0);
      __builtin_amdgcn_global_load_lds(
          (const __attribute__((address_space(1))) void*)(B + (size_t)(bn + r) * K + k0 + scol),
          (__attribute__((address_space(3))) void*)(&sB[(it * 64 + wave * 16) * 32]),
          16, 0, 0);
    }
    __syncthreads();

    s8v af[4], bf[4];
#pragma unroll
    for (int m = 0; m < 4; ++m)
      af[m] = *(const s8v*)&sA[(wm + m * 16 + fr) * 32 + fg * 8];
#pragma unroll
    for (int n = 0; n < 4; ++n)
      bf[n] = *(const s8v*)&sB[(wn + n * 16 + fr) * 32 + fg * 8];
#pragma unroll
    for (int m = 0; m < 4; ++m)
#pragma unroll
      for (int n = 0; n < 4; ++n)
        acc[m][n] = __builtin_amdgcn_mfma_f32_16x16x32_bf16(af[m], bf[n], acc[m][n], 0, 0, 0);
  }

#pragma unroll
  for (int m = 0; m < 4; ++m)
#pragma unroll
    for (int n = 0; n < 4; ++n)
#pragma unroll
      for (int rr = 0; rr < 4; ++rr) {
        int row = bm + wm + m * 16 + fg * 4 + rr;
        int col = bn + wn + n * 16 + fr;
        C[(size_t)row * N + col] = f2b(acc[m][n][rr]);
      }
}

// ---------------- add2: out[i] = P0[i] + P1[i] (bf16 partials -> f32 out) ----------------
__global__ void add2(const ushort_t* __restrict__ a, const ushort_t* __restrict__ b,
                     float* __restrict__ out) {
  int i = blockIdx.x * blockDim.x + threadIdx.x;  // 1M quads of 4
  uint2 pa = ((const uint2*)a)[i];
  uint2 pb = ((const uint2*)b)[i];
  float4 o;
  o.x = b2f((ushort_t)(pa.x & 0xFFFF)) + b2f((ushort_t)(pb.x & 0xFFFF));
  o.y = b2f((ushort_t)(pa.x >> 16))    + b2f((ushort_t)(pb.x >> 16));
  o.z = b2f((ushort_t)(pa.y & 0xFFFF)) + b2f((ushort_t)(pb.y & 0xFFFF));
  o.w = b2f((ushort_t)(pa.y >> 16))    + b2f((ushort_t)(pb.y >> 16));
  ((float4*)out)[i] = o;
}

// ---------------- RoPE on q,k (sums bf16 qkv partials; K written FRAGMENT-PACKED) ----------------
// Kp[kvh][t][n][c][lane=fg*16+fr][8]: value = K[krow(fr,n)+t*64][kvh][c*32+fg*8+j],
// krow perm = 32*(n>>1)+8*(fr>>2)+4*(n&1)+(fr&3)  (inverted here from s).
__global__ void rope_qk(const ushort_t* __restrict__ P0, const ushort_t* __restrict__ P1,
                        const float* __restrict__ fc,
                        ushort_t* __restrict__ Qb, ushort_t* __restrict__ Kp) {
  int tid = blockIdx.x * blockDim.x + threadIdx.x;
  if (tid >= S_LEN * 160) return;           // (NH+NKV) heads * 4 parts of 16
  int s = tid / 160, c = tid - s * 160;
  int h = c >> 2, part = c & 3;
  size_t off = (size_t)s * DQKV + h * 64 + part * 16;
  s8v a0 = *(const s8v*)(P0 + off);
  s8v a1 = *(const s8v*)(P0 + off + 8);
  s8v b0 = *(const s8v*)(P1 + off);
  s8v b1 = *(const s8v*)(P1 + off + 8);
  float xv[16];
#pragma unroll
  for (int i = 0; i < 8; ++i) {
    xv[i]     = b2f((ushort_t)a0[i]) + b2f((ushort_t)b0[i]);
    xv[8 + i] = b2f((ushort_t)a1[i]) + b2f((ushort_t)b1[i]);
  }
  const float* fp = fc + s * 64 + part * 16;
  float fv[16];
  ((float4*)fv)[0] = ((const float4*)fp)[0];
  ((float4*)fv)[1] = ((const float4*)fp)[1];
  ((float4*)fv)[2] = ((const float4*)fp)[2];
  ((float4*)fv)[3] = ((const float4*)fp)[3];
  const float scale = (h < NH) ? QSCALE : 1.0f;
  ushort_t obuf[16];
#pragma unroll
  for (int i = 0; i < 8; ++i) {
    float x0 = xv[2 * i], x1 = xv[2 * i + 1];
    float cs = fv[2 * i], sn = fv[2 * i + 1];
    obuf[2 * i]     = f2b((x0 * cs - x1 * sn) * scale);
    obuf[2 * i + 1] = f2b((x1 * cs + x0 * sn) * scale);
  }
  if (h < NH) {
    ushort_t* dst = Qb + ((size_t)s * NH + h) * 64 + part * 16;
    *(s8v*)dst = *(const s8v*)&obuf[0];
    *(s8v*)(dst + 8) = *(const s8v*)&obuf[8];
  } else {
    const int kvh = h - NH;
    const int t_ = s >> 6, rloc = s & 63;
    const int n_ = 2 * (rloc >> 5) + ((rloc >> 2) & 1);
    const int fr_ = 4 * ((rloc >> 3) & 3) + (rloc & 3);
    const int c_ = part >> 1;
    const int fg0 = (part & 1) * 2;
    ushort_t* dst = Kp + (size_t)kvh * PK_HEAD + t_ * PK_TILE +
                    (n_ * 2 + c_) * PK_CHUNK + (fg0 * 16 + fr_) * 8;
    *(s8v*)dst = *(const s8v*)&obuf[0];          // fg0,  j=0..7
    *(s8v*)(dst + 128) = *(const s8v*)&obuf[8];  // fg0+1 (+16 lanes * 8)
  }
}

// ---------------- V pack: partial-sum qkv[s][2560+hd] -> Vp fragment-packed ----------------
// Vp[kvh][t][d][c][lane=fg*16+fr][j] = V[t*64+c*32+fg*8+j][kvh*64+d*16+fr]
__global__ void pack_v(const ushort_t* __restrict__ P0, const ushort_t* __restrict__ P1,
                       ushort_t* __restrict__ Vp) {
  __shared__ float t[32][33];
  int hd0 = blockIdx.x * 32, s0 = blockIdx.y * 32;
#pragma unroll
  for (int k = 0; k < 4; ++k) {
    int sy = threadIdx.y + k * 8;
    size_t off = (size_t)(s0 + sy) * DQKV + 2560 + hd0 + threadIdx.x;
    t[sy][threadIdx.x] = b2f(P0[off]) + b2f(P1[off]);
  }
  __syncthreads();
  if (threadIdx.y < 4) {
    const int fg = threadIdx.y;
    const int hdl = (hd0 & 32) + threadIdx.x;   // head-local hd (tile is 32 of 64)
    const int kvh = hd0 >> 6;
    const int d = hdl >> 4, fr = hdl & 15;
    const int tt = s0 >> 6, cc = (s0 >> 5) & 1;
    ushort_t ob[8];
#pragma unroll
    for (int j = 0; j < 8; ++j) ob[j] = f2b(t[fg * 8 + j][threadIdx.x]);
    ushort_t* dst = Vp + (size_t)kvh * PK_HEAD + tt * PK_TILE +
                    (d * 2 + cc) * PK_CHUNK + (fg * 16 + fr) * 8;
    *(s8v*)dst = *(const s8v*)&ob[0];
  }
}

// ---------------- softmax step for one accumulator (in-register, exp2 domain) ----------------
__device__ __forceinline__ void softmax_pack(f4v (&sc)[4], float& m, float& l,
                                             f4v (&y)[4], s8v (&pf)[2], int fg) {
  float pmax = sc[0][0];
#pragma unroll
  for (int n = 0; n < 4; ++n)
#pragma unroll
    for (int r = 0; r < 4; ++r) pmax = fmaxf(pmax, sc[n][r]);
  pmax = fmaxf(pmax, __shfl_xor(pmax, 16));
  pmax = fmaxf(pmax, __shfl_xor(pmax, 32));
  if (!__all(pmax <= m + 8.f)) {            // defer-max (T13), wave-uniform
    float mn = fmaxf(m, pmax);
    float al = exp2f(m - mn);
    m = mn;
    l *= al;
    float aly[4];
#pragma unroll
    for (int rr = 0; rr < 4; ++rr) aly[rr] = __shfl(al, fg * 4 + rr);
#pragma unroll
    for (int d = 0; d < 4; ++d)
#pragma unroll
      for (int rr = 0; rr < 4; ++rr) y[d][rr] *= aly[rr];
  }
  float rs = 0.f;
#pragma unroll
  for (int n = 0; n < 4; ++n)
#pragma unroll
    for (int r = 0; r < 4; ++r) {
      float p = exp2f(sc[n][r] - m);
      sc[n][r] = p;
      rs += p;
    }
  l += rs;                                   // per-lane partial; reduced at finalize
#pragma unroll
  for (int c = 0; c < 2; ++c) {
    unsigned wb[4];
    wb[0] = cvtpk(sc[2 * c][0], sc[2 * c][1]);
    wb[1] = cvtpk(sc[2 * c][2], sc[2 * c][3]);
    wb[2] = cvtpk(sc[2 * c + 1][0], sc[2 * c + 1][1]);
    wb[3] = cvtpk(sc[2 * c + 1][2], sc[2 * c + 1][3]);
    pf[c] = *(const s8v*)&wb[0];
  }
}

__device__ __forceinline__ void finalize_y(f4v (&y)[4], float l, int q0, int head,
                                           int fr, int fg, ushort_t* __restrict__ Y) {
  l += __shfl_xor(l, 16);
  l += __shfl_xor(l, 32);
  float linv[4];
#pragma unroll
  for (int rr = 0; rr < 4; ++rr) linv[rr] = 1.f / __shfl(l, fg * 4 + rr);
#pragma unroll
  for (int d = 0; d < 4; ++d)
#pragma unroll
    for (int rr = 0; rr < 4; ++rr)
      Y[(size_t)(q0 + fg * 4 + rr) * HID + head * 64 + d * 16 + fr] =
          f2b(y[d][rr] * linv[rr]);
}

// ---------------- causal GQA flash attention: paired q-tiles + 2-wave kv-split ----------------
// K/V are fragment-packed (Kp/Vp): every fragment load = base + lane*16B,
// fully coalesced 1KB wave loads (kills the 16-row scatter TA cost).
__global__ __launch_bounds__(128) void attn(
    const ushort_t* __restrict__ Q, const ushort_t* __restrict__ Kp,
    const ushort_t* __restrict__ Vp, ushort_t* __restrict__ Y) {
  __shared__ float Lm[2][64];
  __shared__ float Ll[2][64];
  __shared__ float Ly[2][64][17];           // +1 pad: stride 17 -> conflict-free
  const int head = blockIdx.y, kvh = head >> 2;
  const int w = threadIdx.x >> 6;           // wave id 0/1
  const int lane = threadIdx.x & 63;
  const int fr = lane & 15, fg = lane >> 4;
  const int jA = 127 - (int)blockIdx.x;     // long q-tile
  const int jB = (int)blockIdx.x;           // short q-tile
  const int q0A = jA * 16, q0B = jB * 16;
  const int ntA = (q0A >> 6) + 1, ntB = (q0B >> 6) + 1;
  const ushort_t* Kh = Kp + (size_t)kvh * PK_HEAD + lane * 8;
  const ushort_t* Vh = Vp + (size_t)kvh * PK_HEAD + lane * 8;

  s8v qfA[2], qfB[2];
#pragma unroll
  for (int c = 0; c < 2; ++c) {
    qfA[c] = *(const s8v*)(Q + ((size_t)(q0A + fr) * NH + head) * 64 + c * 32 + fg * 8);
    qfB[c] = *(const s8v*)(Q + ((size_t)(q0B + fr) * NH + head) * 64 + c * 32 + fg * 8);
  }

  float mA = -3.0e38f, lA = 0.f, mB = -3.0e38f, lB = 0.f;
  f4v yA[4], yB[4];
#pragma unroll
  for (int d = 0; d < 4; ++d) {
    yA[d] = (f4v){0.f, 0.f, 0.f, 0.f};
    yB[d] = (f4v){0.f, 0.f, 0.f, 0.f};
  }

  for (int t = w; t < ntA; t += 2) {
    const int kv0 = t * 64;
    const bool doB = (t < ntB);             // wave-uniform
    const ushort_t* kt = Kh + t * PK_TILE;
    const ushort_t* vt = Vh + t * PK_TILE;
    // ---- K fragments: packed, coalesced ----
    s8v kf[4][2];
#pragma unroll
    for (int n = 0; n < 4; ++n) {
      kf[n][0] = *(const s8v*)(kt + (n * 2 + 0) * PK_CHUNK);
      kf[n][1] = *(const s8v*)(kt + (n * 2 + 1) * PK_CHUNK);
    }
    // ---- S^T[kv][q] for both q-tiles ----
    f4v scA[4], scB[4];
#pragma unroll
    for (int n = 0; n < 4; ++n) {
      f4v a = (f4v){0.f, 0.f, 0.f, 0.f};
      a = __builtin_amdgcn_mfma_f32_16x16x32_bf16(kf[n][0], qfA[0], a, 0, 0, 0);
      a = __builtin_amdgcn_mfma_f32_16x16x32_bf16(kf[n][1], qfA[1], a, 0, 0, 0);
      scA[n] = a;
    }
    if (doB) {
#pragma unroll
      for (int n = 0; n < 4; ++n) {
        f4v a = (f4v){0.f, 0.f, 0.f, 0.f};
        a = __builtin_amdgcn_mfma_f32_16x16x32_bf16(kf[n][0], qfB[0], a, 0, 0, 0);
        a = __builtin_amdgcn_mfma_f32_16x16x32_bf16(kf[n][1], qfB[1], a, 0, 0, 0);
        scB[n] = a;
      }
    }
    // ---- causal masks (permuted kv index) ----
    if (t == ntA - 1) {
#pragma unroll
      for (int n = 0; n < 4; ++n)
#pragma unroll
        for (int r = 0; r < 4; ++r) {
          int kv = kv0 + 32 * (n >> 1) + 8 * fg + 4 * (n & 1) + r;
          if (kv > q0A + fr) scA[n][r] = -1e30f;
        }
    }
    if (doB && t == ntB - 1) {
#pragma unroll
      for (int n = 0; n < 4; ++n)
#pragma unroll
        for (int r = 0; r < 4; ++r) {
          int kv = kv0 + 32 * (n >> 1) + 8 * fg + 4 * (n & 1) + r;
          if (kv > q0B + fr) scB[n][r] = -1e30f;
        }
    }
    // ---- softmax + pack ----
    s8v pfA[2], pfB[2];
    softmax_pack(scA, mA, lA, yA, pfA, fg);
    if (doB) softmax_pack(scB, mB, lB, yB, pfB, fg);
    // ---- PV with packed V fragments ----
#pragma unroll
    for (int d = 0; d < 4; ++d) {
      s8v vf0 = *(const s8v*)(vt + (d * 2 + 0) * PK_CHUNK);
      s8v vf1 = *(const s8v*)(vt + (d * 2 + 1) * PK_CHUNK);
      yA[d] = __builtin_amdgcn_mfma_f32_16x16x32_bf16(pfA[0], vf0, yA[d], 0, 0, 0);
      yA[d] = __builtin_amdgcn_mfma_f32_16x16x32_bf16(pfA[1], vf1, yA[d], 0, 0, 0);
      if (doB) {
        yB[d] = __builtin_amdgcn_mfma_f32_16x16x32_bf16(pfB[0], vf0, yB[d], 0, 0, 0);
        yB[d] = __builtin_amdgcn_mfma_f32_16x16x32_bf16(pfB[1], vf1, yB[d], 0, 0, 0);
      }
    }
  }

  // ---- cross-wave merge: wave0 stores B-state, wave1 stores A-state ----
  if (w == 0) {
    Lm[1][lane] = mB; Ll[1][lane] = lB;
#pragma unroll
    for (int d = 0; d < 4; ++d)
#pragma unroll
      for (int rr = 0; rr < 4; ++rr) Ly[1][lane][d * 4 + rr] = yB[d][rr];
  } else {
    Lm[0][lane] = mA; Ll[0][lane] = lA;
#pragma unroll
    for (int d = 0; d < 4; ++d)
#pragma unroll
      for (int rr = 0; rr < 4; ++rr) Ly[0][lane][d * 4 + rr] = yA[d][rr];
  }
  __syncthreads();
  if (w == 0) {
    float m1 = Lm[0][lane], l1 = Ll[0][lane];
    float mm = fmaxf(mA, m1);
    float s0 = exp2f(mA - mm), s1 = exp2f(m1 - mm);
    float lm = lA * s0 + l1 * s1;
    float s0y[4], s1y[4];
#pragma unroll
    for (int rr = 0; rr < 4; ++rr) {
      s0y[rr] = __shfl(s0, fg * 4 + rr);
      s1y[rr] = __shfl(s1, fg * 4 + rr);
    }
#pragma unroll
    for (int d = 0; d < 4; ++d)
#pragma unroll
      for (int rr = 0; rr < 4; ++rr)
        yA[d][rr] = yA[d][rr] * s0y[rr] + Ly[0][lane][d * 4 + rr] * s1y[rr];
    finalize_y(yA, lm, q0A, head, fr, fg, Y);
  } else {
    float m1 = Lm[1][lane], l1 = Ll[1][lane];
    float mm = fmaxf(mB, m1);
    float s0 = exp2f(mB - mm), s1 = exp2f(m1 - mm);
    float lm = lB * s0 + l1 * s1;
    float s0y[4], s1y[4];
#pragma unroll
    for (int rr = 0; rr < 4; ++rr) {
      s0y[rr] = __shfl(s0, fg * 4 + rr);
      s1y[rr] = __shfl(s1, fg * 4 + rr);
    }
#pragma unroll
    for (int d = 0; d < 4; ++d)
#pragma unroll
      for (int rr = 0; rr < 4; ++rr)
        yB[d][rr] = yB[d][rr] * s0y[rr] + Ly[1][lane][d * 4 + rr] * s1y[rr];
    finalize_y(yB, lm, q0B, head, fr, fg, Y);
  }
}

// ---------------- launch ----------------
extern "C" void kernel_launch(void* const* d_in, const int* in_sizes, int n_in,
                              void* d_out, int out_size, void* d_ws, size_t ws_size,
                              hipStream_t stream) {
  const float* x    = (const float*)d_in[0];
  const float* fc   = (const float*)d_in[1];
  const float* wqkv = (const float*)d_in[3];
  const float* wo   = (const float*)d_in[4];
  float* out = (float*)d_out;

  char* ws = (char*)d_ws;
  ushort_t* xb    = (ushort_t*)(ws);               // 8 MB; reused as Y after attn
  ushort_t* wqkvb = (ushort_t*)(ws + 8388608);     // 12 MB; dead after GEMM1:
  ushort_t* Qb    = (ushort_t*)(ws + 8388608);     //   Q (8 MB) aliases it
  ushort_t* Kpb   = (ushort_t*)(ws + 16777216);    //   Kp (2 MB, fragment-packed)
  ushort_t* Vpb   = (ushort_t*)(ws + 18874368);    //   Vp (2 MB, fragment-packed)
  ushort_t* wob   = (ushort_t*)(ws + 20971520);    // 8 MB -> ends 28 MiB
  ushort_t* P0    = (ushort_t*)(ws + 29360128);    // 12 MiB qkv partial (z=0)
  ushort_t* P1    = (ushort_t*)(ws + 41943040);    // 12 MiB qkv partial (z=1) -> 52 MiB
  ushort_t* G0    = (ushort_t*)(ws + 29360128);    // 8 MiB out partial (aliases P0, dead)
  ushort_t* G1    = (ushort_t*)(ws + 37748736);    // 8 MiB out partial
  ushort_t* Yb    = xb;

  cvt3<<<14336, 256, 0, stream>>>(x, wqkv, wo, xb, wqkvb, wob);

  gemm_bt_sk<<<dim3(24, 16, 2), 256, 0, stream>>>(xb, wqkvb, P0, P1, 2048, 3072, 2048);

  rope_qk<<<1280, 256, 0, stream>>>(P0, P1, fc, Qb, Kpb);
  pack_v<<<dim3(16, 64), dim3(32, 8), 0, stream>>>(P0, P1, Vpb);

  attn<<<dim3(64, 32), 128, 0, stream>>>(Qb, Kpb, Vpb, Yb);

  gemm_bt_sk<<<dim3(16, 16, 2), 256, 0, stream>>>(Yb, wob, G0, G1, 2048, 2048, 2048);

  add2<<<4096, 256, 0, stream>>>(G0, G1, out);
}